// Round 1
// baseline (1495.462 us; speedup 1.0000x reference)
//
#include <hip/hip_runtime.h>
#include <cstdint>

// ---------------- problem constants ----------------
#define NYD   256
#define NXD   256
#define PMLW  20
#define PADC  22            // PML + FD_PAD
#define NYP_  300           // NY + 2*PAD
#define NXP_  300
#define GD    4             // zero guard ring width (covers radius-4 dependency)
#define ST    308           // padded stride = NYP_ + 2*GD
#define NTT   250
#define NSHOT_ 2
#define NSRC_  8
#define NREC_  64
#define DT_   0.0005f

// ---------------- zero workspace ----------------
__global__ void zero_kernel(float* __restrict__ p, long n) {
    long i = (long)blockIdx.x * blockDim.x + threadIdx.x;
    long stride = (long)gridDim.x * blockDim.x;
    for (; i < n; i += stride) p[i] = 0.0f;
}

// ---------------- one-time setup: v2dt2, PML profiles, src/rec masks ----------------
__global__ void populate_kernel(const float* __restrict__ v,
                                const int* __restrict__ srcloc,
                                const int* __restrict__ recloc,
                                float* __restrict__ v2dt2,
                                float* __restrict__ prof,   // [2*ST]: a (guarded), b (guarded)
                                unsigned* __restrict__ srcmask,
                                unsigned long long* __restrict__ recmask) {
    const long f = (long)ST * ST;
    int i = blockIdx.x * 256 + threadIdx.x;

    if (i < NYP_ * NXP_) {
        int y = i / NXP_, x = i % NXP_;
        int vy = min(max(y - PADC, 0), NYD - 1);
        int vx = min(max(x - PADC, 0), NXD - 1);
        float vv = v[vy * NXD + vx];
        v2dt2[(y + GD) * ST + (x + GD)] = vv * vv * (DT_ * DT_);
    }

    if (i < NYP_) {  // DY == DX and NYP == NXP, so one profile pair serves both axes
        float fi = (float)i;
        float d = fmaxf(22.0f - fi, fi - 277.0f);
        float frac = fminf(fmaxf(d * (1.0f / 20.0f), 0.0f), 1.0f);
        float sigma_max = 3.0f * 4000.0f * logf(1000.0f) / (2.0f * 20.0f * 5.0f);
        float sigma = sigma_max * frac * frac;
        float alpha = 3.14159265358979323846f * 25.0f * (1.0f - frac);
        float b = expf(-(sigma + alpha) * DT_);
        float a = sigma / (sigma + alpha + 1e-9f) * (b - 1.0f);
        prof[GD + i] = a;        // guard entries stay 0 from zero_kernel
        prof[ST + GD + i] = b;
    }

    if (i < NSHOT_ * NSRC_) {
        int sy = srcloc[2 * i] + PADC;
        int sx = srcloc[2 * i + 1] + PADC;
        int shot = i / NSRC_;
        int s = i % NSRC_;
        atomicOr(&srcmask[shot * f + (long)(sy + GD) * ST + (sx + GD)], 1u << s);
    }

    if (i >= 1024 && i < 1024 + NSHOT_ * NREC_) {
        int j = i - 1024;
        int ry = recloc[2 * j] + PADC;
        int rx = recloc[2 * j + 1] + PADC;
        int shot = j / NREC_;
        int r = j % NREC_;
        atomicOr(&recmask[shot * f + (long)(ry + GD) * ST + (rx + GD)], 1ull << r);
    }
}

// ---------------- one time step ----------------
// Halo recompute: psi_new at y±2 / x±2 is recomputed from wfc (radius 4) so a
// single kernel per step has no intra-step dependency. wf and psi ping-pong;
// zeta updates in place (self-cell only). Guard ring (GD=4, always zero)
// implements the reference's zero-padded FD boundaries without bounds checks.
__global__ __launch_bounds__(256) void step_kernel(
    const float* __restrict__ wfc_all,  float* __restrict__ wfn_all,   // read wfm / write wfp
    const float* __restrict__ psiyr_all, float* __restrict__ psiyw_all,
    const float* __restrict__ psixr_all, float* __restrict__ psixw_all,
    float* __restrict__ zetay_all, float* __restrict__ zetax_all,
    const float* __restrict__ v2dt2, const float* __restrict__ prof,
    const unsigned* __restrict__ srcmask,
    const unsigned long long* __restrict__ recmask,
    const float* __restrict__ amps,   // [NSHOT][NSRC][NT]
    float* __restrict__ out,          // [NSHOT][NREC][NT]
    int t) {
    int x = blockIdx.x * 64 + threadIdx.x;
    int y = blockIdx.y * 4 + threadIdx.y;
    int shot = blockIdx.z;
    if (x >= NXP_ || y >= NYP_) return;

    const long f = (long)ST * ST;
    const float* wfc   = wfc_all   + shot * f;
    float*       wfn   = wfn_all   + shot * f;
    const float* psiyr = psiyr_all + shot * f;
    float*       psiyw = psiyw_all + shot * f;
    const float* psixr = psixr_all + shot * f;
    float*       psixw = psixw_all + shot * f;
    float*       zetay = zetay_all + shot * f;
    float*       zetax = zetax_all + shot * f;

    const int c = (y + GD) * ST + (x + GD);

    float wy[9], wx[9];
#pragma unroll
    for (int k = 0; k < 9; k++) wy[k] = wfc[c + (k - 4) * ST];
#pragma unroll
    for (int k = 0; k < 9; k++) wx[k] = (k == 4) ? wy[4] : wfc[c + (k - 4)];

    const float inv_h  = 0.2f;    // 1/DY
    const float inv_h2 = 0.04f;   // 1/DY^2
    const float C1A = 2.0f / 3.0f, C1B = 1.0f / 12.0f;
    const float C2A = 4.0f / 3.0f, C2B = -1.0f / 12.0f, C2C = -2.5f;

    float d2y = (C2B * (wy[2] + wy[6]) + C2A * (wy[3] + wy[5]) + C2C * wy[4]) * inv_h2;
    float d2x = (C2B * (wx[2] + wx[6]) + C2A * (wx[3] + wx[5]) + C2C * wx[4]) * inv_h2;

    float dwdy[5], dwdx[5];
#pragma unroll
    for (int j = 0; j < 5; j++) {
        dwdy[j] = (C1A * (wy[j + 3] - wy[j + 1]) - C1B * (wy[j + 4] - wy[j])) * inv_h;
        dwdx[j] = (C1A * (wx[j + 3] - wx[j + 1]) - C1B * (wx[j + 4] - wx[j])) * inv_h;
    }

    float pny[5], pnx[5];
#pragma unroll
    for (int j = 0; j < 5; j++) {
        int yy = y + j - 2;               // prof guard entries are zero -> psi_new=0 outside
        float ayj = prof[GD + yy];
        float byj = prof[ST + GD + yy];
        pny[j] = byj * psiyr[c + (j - 2) * ST] + ayj * dwdy[j];
        int xx = x + j - 2;
        float axj = prof[GD + xx];
        float bxj = prof[ST + GD + xx];
        pnx[j] = bxj * psixr[c + (j - 2)] + axj * dwdx[j];
    }

    float dpsiy = (C1A * (pny[3] - pny[1]) - C1B * (pny[4] - pny[0])) * inv_h;
    float dpsix = (C1A * (pnx[3] - pnx[1]) - C1B * (pnx[4] - pnx[0])) * inv_h;

    float ay_ = prof[GD + y], by_ = prof[ST + GD + y];
    float ax_ = prof[GD + x], bx_ = prof[ST + GD + x];

    float zy = by_ * zetay[c] + ay_ * (d2y + dpsiy);
    float zx = bx_ * zetax[c] + ax_ * (d2x + dpsix);

    float lap = d2y + d2x + dpsiy + dpsix + zy + zx;
    float vd  = v2dt2[(y + GD) * ST + (x + GD)];
    float wfp = 2.0f * wy[4] - wfn[c] + vd * lap;

    // source injection (owner thread), before store & record — matches reference order
    unsigned sm = srcmask[shot * f + c];
    if (sm) {
#pragma unroll
        for (int s = 0; s < NSRC_; s++)
            if (sm & (1u << s)) wfp += vd * amps[(shot * NSRC_ + s) * NTT + t];
    }

    wfn[c]   = wfp;
    psiyw[c] = pny[2];
    psixw[c] = pnx[2];
    zetay[c] = zy;
    zetax[c] = zx;

    unsigned long long rm = recmask[shot * f + c];
    while (rm) {
        int r = __ffsll((unsigned long long)rm) - 1;
        out[(shot * NREC_ + r) * NTT + t] = wfp;
        rm &= rm - 1;
    }
}

// ---------------- host ----------------
extern "C" void kernel_launch(void* const* d_in, const int* in_sizes, int n_in,
                              void* d_out, int out_size, void* d_ws, size_t ws_size,
                              hipStream_t stream) {
    const float* v      = (const float*)d_in[0];
    const float* amps   = (const float*)d_in[1];
    const int*   srcloc = (const int*)d_in[2];
    const int*   recloc = (const int*)d_in[3];
    float* out = (float*)d_out;

    const long f = (long)ST * ST;
    float* base  = (float*)d_ws;
    float* wf0   = base;             // 2 shots each
    float* wf1   = wf0   + 2 * f;
    float* psiy0 = wf1   + 2 * f;
    float* psiy1 = psiy0 + 2 * f;
    float* psix0 = psiy1 + 2 * f;
    float* psix1 = psix0 + 2 * f;
    float* zetay = psix1 + 2 * f;
    float* zetax = zetay + 2 * f;
    float* v2dt2 = zetax + 2 * f;    // f (shot-independent)
    float* prof  = v2dt2 + f;        // 2*ST
    unsigned* srcmask = (unsigned*)(prof + 2 * ST);              // 2f uints
    unsigned long long* recmask = (unsigned long long*)(srcmask + 2 * f);  // 2f ull

    const long total_words = 23 * f + 2 * ST;  // fields + v2dt2 + prof + masks (ull = 2 words)

    zero_kernel<<<4096, 256, 0, stream>>>(base, total_words);
    populate_kernel<<<(NYP_ * NXP_ + 255) / 256, 256, 0, stream>>>(
        v, srcloc, recloc, v2dt2, prof, srcmask, recmask);

    dim3 blk(64, 4, 1);
    dim3 grd((NXP_ + 63) / 64, (NYP_ + 3) / 4, NSHOT_);
    for (int t = 0; t < NTT; t++) {
        const float* wc  = (t & 1) ? wf1 : wf0;
        float*       wn  = (t & 1) ? wf0 : wf1;
        const float* pyr = (t & 1) ? psiy1 : psiy0;
        float*       pyw = (t & 1) ? psiy0 : psiy1;
        const float* pxr = (t & 1) ? psix1 : psix0;
        float*       pxw = (t & 1) ? psix0 : psix1;
        step_kernel<<<grd, blk, 0, stream>>>(wc, wn, pyr, pyw, pxr, pxw,
                                             zetay, zetax, v2dt2, prof,
                                             srcmask, recmask, amps, out, t);
    }
}